// Round 2
// baseline (4609.257 us; speedup 1.0000x reference)
//
#include <hip/hip_runtime.h>
#include <hip/hip_bf16.h>
#include <math.h>

// Problem constants
#define D_   1024
#define HD_  64
#define NH_  16
#define H_   16
#define KH_  8
#define NT_  128      // tokens per chunk (N)
#define E_   4096
#define RE_  4
#define DE_  4
#define ET_  16
#define S_   2048
#define T_   2048
#define BC_  16
#define EPS_ 1e-5f

// ---------------------------------------------------------------------------
// rmsnorm: out[row,:] = x[row,:] * rsqrt(mean(x^2)+eps) * w   (all fp32)
// ---------------------------------------------------------------------------
__global__ __launch_bounds__(256) void rmsnorm_kernel(
    const float* __restrict__ x, const float* __restrict__ w,
    float* __restrict__ out)
{
    int row = blockIdx.x, tid = threadIdx.x;
    __shared__ float sred[4];
    float4 v = ((const float4*)(x + (size_t)row * D_))[tid];
    float ss = v.x*v.x + v.y*v.y + v.z*v.z + v.w*v.w;
#pragma unroll
    for (int off = 32; off > 0; off >>= 1) ss += __shfl_xor(ss, off);
    if ((tid & 63) == 0) sred[tid >> 6] = ss;
    __syncthreads();
    float tot = sred[0] + sred[1] + sred[2] + sred[3];
    float scale = rsqrtf(tot * (1.0f / D_) + EPS_);
    float4 wv = ((const float4*)w)[tid];
    float4 o;
    o.x = v.x * scale * wv.x;
    o.y = v.y * scale * wv.y;
    o.z = v.z * scale * wv.z;
    o.w = v.w * scale * wv.w;
    ((float4*)(out + (size_t)row * D_))[tid] = o;
}

// ---------------------------------------------------------------------------
// GEMM: C[M,N] = A[M,K] @ B[K,N]  [+ res], all fp32
// tile 128x64, BK=16, 256 threads, 8x4 per thread
// ---------------------------------------------------------------------------
#define BM 128
#define BN 64
#define BK 16
__global__ __launch_bounds__(256) void gemm_kernel(
    const float* __restrict__ A, const float* __restrict__ Bw,
    const float* __restrict__ res, float* __restrict__ C,
    int M, int N, int K)
{
    __shared__ float As[BK][BM + 1];
    __shared__ float Bs[BK][BN + 1];
    int tid = threadIdx.x;
    int tx = tid & 15, ty = tid >> 4;
    int bn = blockIdx.x * BN, bm = blockIdx.y * BM;
    float acc[8][4];
#pragma unroll
    for (int i = 0; i < 8; i++)
#pragma unroll
        for (int j = 0; j < 4; j++) acc[i][j] = 0.0f;
    int arow = tid >> 4;   // 0..15
    int acol = tid & 15;   // k within tile
    int brow = tid >> 6;   // 0..3
    int bcol = tid & 63;
    for (int k0 = 0; k0 < K; k0 += BK) {
#pragma unroll
        for (int i = 0; i < 8; i++) {
            int r = arow + 16 * i;
            As[acol][r] = A[(size_t)(bm + r) * K + k0 + acol];
        }
#pragma unroll
        for (int i = 0; i < 4; i++) {
            int kk = brow + 4 * i;
            Bs[kk][bcol] = Bw[(size_t)(k0 + kk) * N + bn + bcol];
        }
        __syncthreads();
#pragma unroll
        for (int kk = 0; kk < BK; kk++) {
            float av[8], bv[4];
#pragma unroll
            for (int i = 0; i < 8; i++) av[i] = As[kk][ty * 8 + i];
#pragma unroll
            for (int j = 0; j < 4; j++) bv[j] = Bs[kk][tx * 4 + j];
#pragma unroll
            for (int i = 0; i < 8; i++)
#pragma unroll
                for (int j = 0; j < 4; j++)
                    acc[i][j] += av[i] * bv[j];
        }
        __syncthreads();
    }
#pragma unroll
    for (int i = 0; i < 8; i++) {
        int row = bm + ty * 8 + i;
#pragma unroll
        for (int j = 0; j < 4; j++) {
            int col = bn + tx * 4 + j;
            float v = acc[i][j];
            if (res) v += res[(size_t)row * N + col];
            C[(size_t)row * N + col] = v;
        }
    }
}

// ---------------------------------------------------------------------------
// qkv prep: split qkv rows into per-head (NH,S,HD) q/k/v with l2norm + rope
// one wave per (s,h); lane = dim
// ---------------------------------------------------------------------------
__global__ __launch_bounds__(64) void qkv_prep_kernel(
    const float* __restrict__ qkv, float* __restrict__ qh,
    float* __restrict__ khb, float* __restrict__ vhb)
{
    int bid = blockIdx.x;
    int s = bid / NH_, h = bid % NH_;
    int lane = threadIdx.x;

    size_t qoff = (size_t)s * (3 * D_) + h * HD_ + lane;
    float qv = qkv[qoff];
    float kv = qkv[qoff + D_];
    float vv = qkv[qoff + 2 * D_];

    // l2 norm (over the 64-dim head == the wave)
    float sq = qv * qv, sk = kv * kv;
#pragma unroll
    for (int off = 32; off > 0; off >>= 1) {
        sq += __shfl_xor(sq, off);
        sk += __shfl_xor(sk, off);
    }
    qv /= fmaxf(sqrtf(sq), EPS_);
    kv /= fmaxf(sqrtf(sk), EPS_);

    // rope: pairs (i, i+32); freq index j = lane & 31
    int j = lane & 31;
    float sign = (lane < 32) ? 1.0f : -1.0f;
    // inv_freq = (1/10000)^(j/32) = exp2(j * log2(1e-4)/32)
    float inv_freq = exp2f((float)j * (-13.287712379549449f / 32.0f));
    float f = (float)s * inv_freq;
    float sn, cs;
    sincosf(f, &sn, &cs);
    float qo = __shfl_xor(qv, 32);
    float ko = __shfl_xor(kv, 32);
    qv = qv * cs + sign * qo * sn;
    kv = kv * cs + sign * ko * sn;

    size_t o = ((size_t)h * S_ + s) * HD_ + lane;
    qh[o] = qv;
    khb[o] = kv;
    vhb[o] = vv;
}

// ---------------------------------------------------------------------------
// causal attention, online softmax; one wave handles 4 queries of one head;
// lane = dim (HD==64==wave)
// ---------------------------------------------------------------------------
__global__ __launch_bounds__(64) void attn_kernel(
    const float* __restrict__ qh, const float* __restrict__ khb,
    const float* __restrict__ vhb, float* __restrict__ ao)
{
    int bid = blockIdx.x;
    int h = bid / (S_ / 4);
    int q0 = (bid % (S_ / 4)) * 4;
    int lane = threadIdx.x;
    const float* Kb = khb + (size_t)h * S_ * HD_;
    const float* Vb = vhb + (size_t)h * S_ * HD_;
    float qv[4];
#pragma unroll
    for (int i = 0; i < 4; i++)
        qv[i] = qh[((size_t)h * S_ + q0 + i) * HD_ + lane] * 0.125f; // 1/sqrt(64)
    float m[4] = {-INFINITY, -INFINITY, -INFINITY, -INFINITY};
    float l[4] = {0.f, 0.f, 0.f, 0.f};
    float a[4] = {0.f, 0.f, 0.f, 0.f};
    for (int k = 0; k <= q0 + 3; k++) {
        float kv = Kb[k * HD_ + lane];
        float vv = Vb[k * HD_ + lane];
        float d0 = qv[0] * kv, d1 = qv[1] * kv, d2 = qv[2] * kv, d3 = qv[3] * kv;
#pragma unroll
        for (int off = 32; off > 0; off >>= 1) {
            d0 += __shfl_xor(d0, off);
            d1 += __shfl_xor(d1, off);
            d2 += __shfl_xor(d2, off);
            d3 += __shfl_xor(d3, off);
        }
        float s4[4] = {d0, d1, d2, d3};
#pragma unroll
        for (int i = 0; i < 4; i++) {
            if (k <= q0 + i) {
                float nm = fmaxf(m[i], s4[i]);
                float corr = __expf(m[i] - nm);
                float p = __expf(s4[i] - nm);
                l[i] = l[i] * corr + p;
                a[i] = a[i] * corr + p * vv;
                m[i] = nm;
            }
        }
    }
#pragma unroll
    for (int i = 0; i < 4; i++)
        ao[(size_t)(q0 + i) * D_ + h * HD_ + lane] = a[i] / l[i];
}

// ---------------------------------------------------------------------------
// expert scores + combine weights. One block per (chunk c, expert slot e).
// All 128 tokens of a chunk share idx. Computes
//   dots[t,kh] = xf[t,:] . keys[kh,:,idx]   (ms[t,e,h] with kh=h/2)
//   w[t,e] = sum_h sigmoid(sp0*dots + sp1*scores)*hp
// ---------------------------------------------------------------------------
__global__ __launch_bounds__(256) void expert_score_kernel(
    const float* __restrict__ xf, const float* __restrict__ keys,
    const float* __restrict__ scores,
    const float* __restrict__ head_probs,
    const float* __restrict__ score_probs,
    const int* __restrict__ indices, float* __restrict__ wbuf)
{
    __shared__ float Ks[KH_][D_];     // 32 KB
    __shared__ float Xs[NT_][33];     // 16.9 KB (padded: conflict-free)
    __shared__ float Ds[NT_][9];      // 4.6 KB (padded)
    __shared__ float sp0[H_], sp1[H_], hp[H_];
    int blk = blockIdx.x;
    int c = blk / ET_, e = blk % ET_;
    int tid = threadIdx.x;
    int idx = indices[c * ET_ + e];
    int r = e / DE_;
    for (int i = tid; i < KH_ * D_; i += 256) {
        int kh = i >> 10, d = i & 1023;
        Ks[kh][d] = keys[((size_t)kh * D_ + d) * E_ + idx];
    }
    if (tid < H_) {
        int h = tid;
        // score_probs shape (2,1,RE,E,H)
        sp0[h] = score_probs[((size_t)(0 * RE_ + r) * E_ + idx) * H_ + h];
        sp1[h] = score_probs[((size_t)(1 * RE_ + r) * E_ + idx) * H_ + h];
        hp[h]  = head_probs[((size_t)r * E_ + idx) * H_ + h];
    }
    float acc[4] = {0.f, 0.f, 0.f, 0.f};
    int tl = tid & 127;    // local token
    int g = tid >> 7;      // kh group: kh = g*4 + j
    for (int d0 = 0; d0 < D_; d0 += 32) {
        __syncthreads();
        for (int i = tid; i < NT_ * 32; i += 256) {
            int t = i >> 5, d = i & 31;
            Xs[t][d] = xf[((size_t)(c * NT_ + t)) * D_ + d0 + d];
        }
        __syncthreads();
        for (int d = 0; d < 32; d++) {
            float aval = Xs[tl][d];
#pragma unroll
            for (int j = 0; j < 4; j++)
                acc[j] += aval * Ks[g * 4 + j][d0 + d];
        }
    }
    __syncthreads();
#pragma unroll
    for (int j = 0; j < 4; j++) Ds[tl][g * 4 + j] = acc[j];
    __syncthreads();
    if (tid < NT_) {
        int t = c * NT_ + tid;
        float wsum = 0.f;
#pragma unroll
        for (int h = 0; h < H_; h++) {
            float mval = Ds[tid][h >> 1];
            float sc = scores[((size_t)t * ET_ + e) * H_ + h];
            float z = sp0[h] * mval + sp1[h] * sc;
            float cmb = 1.0f / (1.0f + __expf(-z));
            wsum += cmb * hp[h];
        }
        wbuf[t * ET_ + e] = wsum;
    }
}

// ---------------------------------------------------------------------------
// MoE with rank-1 experts. One block per token. 16 experts; each needs
// h0 = xf.w0, h1 = xf.w1 (block reductions), out += silu(h0)*h1*w * w2.
// Fuses final residual (+x_ffn_input) and fp32 output store.
// ---------------------------------------------------------------------------
__global__ __launch_bounds__(256) void moe_kernel(
    const float* __restrict__ xf, const float* __restrict__ xfi,
    const int* __restrict__ indices, const float* __restrict__ wbuf,
    const float* __restrict__ experts, float* __restrict__ out)
{
    int t = blockIdx.x, tid = threadIdx.x;
    int c = t / NT_;
    __shared__ int sidx[ET_];
    __shared__ float sw[ET_];
    __shared__ float r0[4], r1[4];
    if (tid < ET_) {
        sidx[tid] = indices[c * ET_ + tid];
        sw[tid] = wbuf[t * ET_ + tid];
    }
    float4 xv = ((const float4*)(xf + (size_t)t * D_))[tid];
    float acc[4] = {0.f, 0.f, 0.f, 0.f};
    __syncthreads();
    for (int e = 0; e < ET_; e++) {
        int idx = sidx[e];
        size_t base = (size_t)idx * D_;
        float4 w0 = *(const float4*)(experts + base + tid * 4);
        float4 w1 = *(const float4*)(experts + (size_t)E_ * D_ + base + tid * 4);
        float p0 = xv.x * w0.x + xv.y * w0.y + xv.z * w0.z + xv.w * w0.w;
        float p1 = xv.x * w1.x + xv.y * w1.y + xv.z * w1.z + xv.w * w1.w;
#pragma unroll
        for (int off = 32; off > 0; off >>= 1) {
            p0 += __shfl_xor(p0, off);
            p1 += __shfl_xor(p1, off);
        }
        if ((tid & 63) == 0) { r0[tid >> 6] = p0; r1[tid >> 6] = p1; }
        __syncthreads();
        float h0 = r0[0] + r0[1] + r0[2] + r0[3];
        float h1 = r1[0] + r1[1] + r1[2] + r1[3];
        __syncthreads();   // protect r0/r1 reuse next iteration
        float act = h0 / (1.0f + __expf(-h0)) * h1 * sw[e];  // silu(h0)*h1*w
        float4 w2 = *(const float4*)(experts + (size_t)2 * E_ * D_ + base + tid * 4);
        acc[0] += act * w2.x;
        acc[1] += act * w2.y;
        acc[2] += act * w2.z;
        acc[3] += act * w2.w;
    }
    size_t o = (size_t)t * D_ + tid * 4;
    float4 rv = *(const float4*)(xfi + o);
    float4 ov;
    ov.x = acc[0] + rv.x;
    ov.y = acc[1] + rv.y;
    ov.z = acc[2] + rv.z;
    ov.w = acc[3] + rv.w;
    *(float4*)(out + o) = ov;
}

// ---------------------------------------------------------------------------
extern "C" void kernel_launch(void* const* d_in, const int* in_sizes, int n_in,
                              void* d_out, int out_size, void* d_ws, size_t ws_size,
                              hipStream_t stream)
{
    (void)in_sizes; (void)n_in; (void)out_size; (void)ws_size;
    const float* x_input     = (const float*)d_in[0];
    const int*   indices     = (const int*)d_in[1];
    const float* scores      = (const float*)d_in[2];
    const float* attn_w      = (const float*)d_in[3];
    const float* attn_out_w  = (const float*)d_in[4];
    const float* attn_norm_w = (const float*)d_in[5];
    const float* ffn_norm_w  = (const float*)d_in[6];
    const float* ffn_experts = (const float*)d_in[7];
    const float* keys        = (const float*)d_in[8];
    const float* head_probs  = (const float*)d_in[9];
    const float* score_probs = (const float*)d_in[10];
    float* out = (float*)d_out;

    float* ws = (float*)d_ws;
    const size_t MF = 1024 * 1024;
    // Region map (floats), peak 12M floats = 48 MB:
    //   [0,2M)=A  [2M,8M)=B  [8M,10M)=C  [10M,12M)=D
    float* xn   = ws + 8 * MF;    // C: rmsnorm(x)
    float* qkv  = ws + 2 * MF;    // B[0..6M): T x 3D
    float* qh   = ws + 8 * MF;    // C (xn dead after gemm1)
    float* khb  = ws;             // A
    float* vhb  = ws + 10 * MF;   // D
    float* ao   = ws + 2 * MF;    // B[0..2M) (qkv dead after prep)
    float* xfi  = ws + 4 * MF;    // B[2..4M)
    float* xf   = ws + 6 * MF;    // B[4..6M)
    float* wbuf = ws;             // A (khb dead after attn)

    rmsnorm_kernel<<<T_, 256, 0, stream>>>(x_input, attn_norm_w, xn);

    dim3 g1(3 * D_ / BN, T_ / BM);
    gemm_kernel<<<g1, 256, 0, stream>>>(xn, attn_w, nullptr, qkv, T_, 3 * D_, D_);

    qkv_prep_kernel<<<T_ * NH_, 64, 0, stream>>>(qkv, qh, khb, vhb);

    attn_kernel<<<NH_ * (S_ / 4), 64, 0, stream>>>(qh, khb, vhb, ao);

    dim3 g2(D_ / BN, T_ / BM);
    gemm_kernel<<<g2, 256, 0, stream>>>(ao, attn_out_w, x_input, xfi, T_, D_, D_);

    rmsnorm_kernel<<<T_, 256, 0, stream>>>(xfi, ffn_norm_w, xf);

    expert_score_kernel<<<BC_ * ET_, 256, 0, stream>>>(
        xf, keys, scores, head_probs, score_probs, indices, wbuf);

    moe_kernel<<<T_, 256, 0, stream>>>(xf, xfi, indices, wbuf, ffn_experts, out);
}

// Round 3
// 949.340 us; speedup vs baseline: 4.8552x; 4.8552x over previous
//
#include <hip/hip_runtime.h>
#include <hip/hip_bf16.h>
#include <math.h>

// Problem constants
#define D_   1024
#define HD_  64
#define NH_  16
#define H_   16
#define KH_  8
#define NT_  128      // tokens per chunk (N)
#define E_   4096
#define RE_  4
#define DE_  4
#define ET_  16
#define S_   2048
#define T_   2048
#define BC_  16
#define EPS_ 1e-5f

// ---------------------------------------------------------------------------
// rmsnorm: out[row,:] = x[row,:] * rsqrt(mean(x^2)+eps) * w   (all fp32)
// ---------------------------------------------------------------------------
__global__ __launch_bounds__(256) void rmsnorm_kernel(
    const float* __restrict__ x, const float* __restrict__ w,
    float* __restrict__ out)
{
    int row = blockIdx.x, tid = threadIdx.x;
    __shared__ float sred[4];
    float4 v = ((const float4*)(x + (size_t)row * D_))[tid];
    float ss = v.x*v.x + v.y*v.y + v.z*v.z + v.w*v.w;
#pragma unroll
    for (int off = 32; off > 0; off >>= 1) ss += __shfl_xor(ss, off);
    if ((tid & 63) == 0) sred[tid >> 6] = ss;
    __syncthreads();
    float tot = sred[0] + sred[1] + sred[2] + sred[3];
    float scale = rsqrtf(tot * (1.0f / D_) + EPS_);
    float4 wv = ((const float4*)w)[tid];
    float4 o;
    o.x = v.x * scale * wv.x;
    o.y = v.y * scale * wv.y;
    o.z = v.z * scale * wv.z;
    o.w = v.w * scale * wv.w;
    ((float4*)(out + (size_t)row * D_))[tid] = o;
}

// ---------------------------------------------------------------------------
// GEMM: C[M,N] = A[M,K] @ B[K,N]  [+ res], all fp32
// tile 128x64, BK=16, 256 threads, 8x4 per thread
// ---------------------------------------------------------------------------
#define BM 128
#define BN 64
#define BK 16
__global__ __launch_bounds__(256) void gemm_kernel(
    const float* __restrict__ A, const float* __restrict__ Bw,
    const float* __restrict__ res, float* __restrict__ C,
    int M, int N, int K)
{
    __shared__ float As[BK][BM + 1];
    __shared__ float Bs[BK][BN + 1];
    int tid = threadIdx.x;
    int tx = tid & 15, ty = tid >> 4;
    int bn = blockIdx.x * BN, bm = blockIdx.y * BM;
    float acc[8][4];
#pragma unroll
    for (int i = 0; i < 8; i++)
#pragma unroll
        for (int j = 0; j < 4; j++) acc[i][j] = 0.0f;
    int arow = tid >> 4;   // 0..15
    int acol = tid & 15;   // k within tile
    int brow = tid >> 6;   // 0..3
    int bcol = tid & 63;
    for (int k0 = 0; k0 < K; k0 += BK) {
#pragma unroll
        for (int i = 0; i < 8; i++) {
            int r = arow + 16 * i;
            As[acol][r] = A[(size_t)(bm + r) * K + k0 + acol];
        }
#pragma unroll
        for (int i = 0; i < 4; i++) {
            int kk = brow + 4 * i;
            Bs[kk][bcol] = Bw[(size_t)(k0 + kk) * N + bn + bcol];
        }
        __syncthreads();
#pragma unroll
        for (int kk = 0; kk < BK; kk++) {
            float av[8], bv[4];
#pragma unroll
            for (int i = 0; i < 8; i++) av[i] = As[kk][ty * 8 + i];
#pragma unroll
            for (int j = 0; j < 4; j++) bv[j] = Bs[kk][tx * 4 + j];
#pragma unroll
            for (int i = 0; i < 8; i++)
#pragma unroll
                for (int j = 0; j < 4; j++)
                    acc[i][j] += av[i] * bv[j];
        }
        __syncthreads();
    }
#pragma unroll
    for (int i = 0; i < 8; i++) {
        int row = bm + ty * 8 + i;
#pragma unroll
        for (int j = 0; j < 4; j++) {
            int col = bn + tx * 4 + j;
            float v = acc[i][j];
            if (res) v += res[(size_t)row * N + col];
            C[(size_t)row * N + col] = v;
        }
    }
}

// ---------------------------------------------------------------------------
// qkv prep: split qkv rows into per-head (NH,S,HD) q/k/v with l2norm + rope
// one wave per (s,h); lane = dim
// ---------------------------------------------------------------------------
__global__ __launch_bounds__(64) void qkv_prep_kernel(
    const float* __restrict__ qkv, float* __restrict__ qh,
    float* __restrict__ khb, float* __restrict__ vhb)
{
    int bid = blockIdx.x;
    int s = bid / NH_, h = bid % NH_;
    int lane = threadIdx.x;

    size_t qoff = (size_t)s * (3 * D_) + h * HD_ + lane;
    float qv = qkv[qoff];
    float kv = qkv[qoff + D_];
    float vv = qkv[qoff + 2 * D_];

    // l2 norm (over the 64-dim head == the wave)
    float sq = qv * qv, sk = kv * kv;
#pragma unroll
    for (int off = 32; off > 0; off >>= 1) {
        sq += __shfl_xor(sq, off);
        sk += __shfl_xor(sk, off);
    }
    qv /= fmaxf(sqrtf(sq), EPS_);
    kv /= fmaxf(sqrtf(sk), EPS_);

    // rope: pairs (i, i+32); freq index j = lane & 31
    int j = lane & 31;
    float sign = (lane < 32) ? 1.0f : -1.0f;
    // inv_freq = (1/10000)^(j/32) = exp2(j * log2(1e-4)/32)
    float inv_freq = exp2f((float)j * (-13.287712379549449f / 32.0f));
    float f = (float)s * inv_freq;
    float sn, cs;
    sincosf(f, &sn, &cs);
    float qo = __shfl_xor(qv, 32);
    float ko = __shfl_xor(kv, 32);
    qv = qv * cs + sign * qo * sn;
    kv = kv * cs + sign * ko * sn;

    size_t o = ((size_t)h * S_ + s) * HD_ + lane;
    qh[o] = qv;
    khb[o] = kv;
    vhb[o] = vv;
}

// ---------------------------------------------------------------------------
// Tiled causal flash attention (fp32).
// Block = 256 threads (ty 0..15 x tx 0..15). Each block: one head, TWO
// paired q-tiles (t and 31-t) of 64 queries -> every block does exactly 33
// k-tile iterations (load balance). Per thread: 4x4 S micro-tile, 4x4 O acc.
// Qs/Ks stored transposed [d][row] stride 65 (conflict-free transpose store,
// broadcast reads). Vs/Ps natural [row][col] stride 68 (16B-aligned rows).
// ---------------------------------------------------------------------------
#define NQT_ (S_ / 64)   // 32 q-tiles per head
__global__ __launch_bounds__(256) void flash_attn_kernel(
    const float* __restrict__ qh, const float* __restrict__ khb,
    const float* __restrict__ vhb, float* __restrict__ ao)
{
    __shared__ float Qs[64][65];
    __shared__ float Ks[64][65];
    __shared__ float Vs[64][68];
    __shared__ float Ps[64][68];
    int h = blockIdx.x >> 4;       // head
    int p = blockIdx.x & 15;       // pair index
    int tid = threadIdx.x;
    int ty = tid >> 4, tx = tid & 15;
    const float* Qb = qh  + (size_t)h * S_ * HD_;
    const float* Kb = khb + (size_t)h * S_ * HD_;
    const float* Vb = vhb + (size_t)h * S_ * HD_;

    for (int half = 0; half < 2; half++) {
        int t = half ? (NQT_ - 1 - p) : p;
        int q0 = t * 64;

        // ---- load Q tile, transposed + pre-scaled by 1/sqrt(HD) ----
#pragma unroll
        for (int rr = 0; rr < 4; rr++) {
            int r = ty + 16 * rr;
            float4 qv4 = *(const float4*)(Qb + (size_t)(q0 + r) * HD_ + 4 * tx);
            Qs[4 * tx + 0][r] = qv4.x * 0.125f;
            Qs[4 * tx + 1][r] = qv4.y * 0.125f;
            Qs[4 * tx + 2][r] = qv4.z * 0.125f;
            Qs[4 * tx + 3][r] = qv4.w * 0.125f;
        }

        float m[4], l[4], accO[4][4];
#pragma unroll
        for (int i = 0; i < 4; i++) {
            m[i] = -INFINITY; l[i] = 0.f;
#pragma unroll
            for (int j = 0; j < 4; j++) accO[i][j] = 0.f;
        }

        for (int kt = 0; kt <= t; kt++) {
            int k0 = kt * 64;
            // ---- load K (transposed) and V (natural) tiles ----
#pragma unroll
            for (int rr = 0; rr < 4; rr++) {
                int r = ty + 16 * rr;
                float4 kv4 = *(const float4*)(Kb + (size_t)(k0 + r) * HD_ + 4 * tx);
                Ks[4 * tx + 0][r] = kv4.x;
                Ks[4 * tx + 1][r] = kv4.y;
                Ks[4 * tx + 2][r] = kv4.z;
                Ks[4 * tx + 3][r] = kv4.w;
                float4 vv4 = *(const float4*)(Vb + (size_t)(k0 + r) * HD_ + 4 * tx);
                *(float4*)(&Vs[r][4 * tx]) = vv4;
            }
            __syncthreads();

            // ---- S = Q K^T micro-tile ----
            float acc[4][4];
#pragma unroll
            for (int i = 0; i < 4; i++)
#pragma unroll
                for (int j = 0; j < 4; j++) acc[i][j] = 0.f;
#pragma unroll 8
            for (int d = 0; d < 64; d++) {
                float av[4], bv[4];
#pragma unroll
                for (int i = 0; i < 4; i++) av[i] = Qs[d][4 * ty + i];
#pragma unroll
                for (int j = 0; j < 4; j++) bv[j] = Ks[d][4 * tx + j];
#pragma unroll
                for (int i = 0; i < 4; i++)
#pragma unroll
                    for (int j = 0; j < 4; j++)
                        acc[i][j] += av[i] * bv[j];
            }

            // ---- causal mask on diagonal tile ----
            if (kt == t) {
#pragma unroll
                for (int i = 0; i < 4; i++)
#pragma unroll
                    for (int j = 0; j < 4; j++)
                        if (4 * tx + j > 4 * ty + i) acc[i][j] = -1e30f;
            }

            // ---- online softmax (rowwise over the 16-lane tx group) ----
            float pp[4][4];
#pragma unroll
            for (int i = 0; i < 4; i++) {
                float mt = fmaxf(fmaxf(acc[i][0], acc[i][1]),
                                 fmaxf(acc[i][2], acc[i][3]));
#pragma unroll
                for (int off = 1; off < 16; off <<= 1)
                    mt = fmaxf(mt, __shfl_xor(mt, off));
                float mn = fmaxf(m[i], mt);
                float corr = __expf(m[i] - mn);
                m[i] = mn;
                float rs = 0.f;
#pragma unroll
                for (int j = 0; j < 4; j++) {
                    float pv = __expf(acc[i][j] - mn);
                    pp[i][j] = pv;
                    rs += pv;
                }
#pragma unroll
                for (int off = 1; off < 16; off <<= 1)
                    rs += __shfl_xor(rs, off);
                l[i] = l[i] * corr + rs;
#pragma unroll
                for (int j = 0; j < 4; j++) accO[i][j] *= corr;
            }

            // ---- write P to LDS ----
#pragma unroll
            for (int i = 0; i < 4; i++) {
                float4 pv4 = make_float4(pp[i][0], pp[i][1], pp[i][2], pp[i][3]);
                *(float4*)(&Ps[4 * ty + i][4 * tx]) = pv4;
            }
            __syncthreads();

            // ---- O += P V ----
#pragma unroll 8
            for (int j = 0; j < 64; j++) {
                float4 bv4 = *(const float4*)(&Vs[j][4 * tx]);
#pragma unroll
                for (int i = 0; i < 4; i++) {
                    float pv = Ps[4 * ty + i][j];
                    accO[i][0] += pv * bv4.x;
                    accO[i][1] += pv * bv4.y;
                    accO[i][2] += pv * bv4.z;
                    accO[i][3] += pv * bv4.w;
                }
            }
            __syncthreads();   // before next k-tile overwrites Ks/Vs/Ps
        }

        // ---- epilogue: normalize and store to (T, D) layout ----
#pragma unroll
        for (int i = 0; i < 4; i++) {
            float inv = 1.0f / l[i];
            float4 ov = make_float4(accO[i][0] * inv, accO[i][1] * inv,
                                    accO[i][2] * inv, accO[i][3] * inv);
            *(float4*)(ao + (size_t)(q0 + 4 * ty + i) * D_ + h * HD_ + 4 * tx) = ov;
        }
        __syncthreads();   // Qs reload safety for second half
    }
}

// ---------------------------------------------------------------------------
// expert scores + combine weights. One block per (chunk c, expert slot e).
// ---------------------------------------------------------------------------
__global__ __launch_bounds__(256) void expert_score_kernel(
    const float* __restrict__ xf, const float* __restrict__ keys,
    const float* __restrict__ scores,
    const float* __restrict__ head_probs,
    const float* __restrict__ score_probs,
    const int* __restrict__ indices, float* __restrict__ wbuf)
{
    __shared__ float Ks[KH_][D_];     // 32 KB
    __shared__ float Xs[NT_][33];     // padded: conflict-free
    __shared__ float Ds[NT_][9];      // padded
    __shared__ float sp0[H_], sp1[H_], hp[H_];
    int blk = blockIdx.x;
    int c = blk / ET_, e = blk % ET_;
    int tid = threadIdx.x;
    int idx = indices[c * ET_ + e];
    int r = e / DE_;
    for (int i = tid; i < KH_ * D_; i += 256) {
        int kh = i >> 10, d = i & 1023;
        Ks[kh][d] = keys[((size_t)kh * D_ + d) * E_ + idx];
    }
    if (tid < H_) {
        int h = tid;
        sp0[h] = score_probs[((size_t)(0 * RE_ + r) * E_ + idx) * H_ + h];
        sp1[h] = score_probs[((size_t)(1 * RE_ + r) * E_ + idx) * H_ + h];
        hp[h]  = head_probs[((size_t)r * E_ + idx) * H_ + h];
    }
    float acc[4] = {0.f, 0.f, 0.f, 0.f};
    int tl = tid & 127;    // local token
    int g = tid >> 7;      // kh group: kh = g*4 + j
    for (int d0 = 0; d0 < D_; d0 += 32) {
        __syncthreads();
        for (int i = tid; i < NT_ * 32; i += 256) {
            int t = i >> 5, d = i & 31;
            Xs[t][d] = xf[((size_t)(c * NT_ + t)) * D_ + d0 + d];
        }
        __syncthreads();
        for (int d = 0; d < 32; d++) {
            float aval = Xs[tl][d];
#pragma unroll
            for (int j = 0; j < 4; j++)
                acc[j] += aval * Ks[g * 4 + j][d0 + d];
        }
    }
    __syncthreads();
#pragma unroll
    for (int j = 0; j < 4; j++) Ds[tl][g * 4 + j] = acc[j];
    __syncthreads();
    if (tid < NT_) {
        int t = c * NT_ + tid;
        float wsum = 0.f;
#pragma unroll
        for (int h = 0; h < H_; h++) {
            float mval = Ds[tid][h >> 1];
            float sc = scores[((size_t)t * ET_ + e) * H_ + h];
            float z = sp0[h] * mval + sp1[h] * sc;
            float cmb = 1.0f / (1.0f + __expf(-z));
            wsum += cmb * hp[h];
        }
        wbuf[t * ET_ + e] = wsum;
    }
}

// ---------------------------------------------------------------------------
// MoE with rank-1 experts. One block per token.
// ---------------------------------------------------------------------------
__global__ __launch_bounds__(256) void moe_kernel(
    const float* __restrict__ xf, const float* __restrict__ xfi,
    const int* __restrict__ indices, const float* __restrict__ wbuf,
    const float* __restrict__ experts, float* __restrict__ out)
{
    int t = blockIdx.x, tid = threadIdx.x;
    int c = t / NT_;
    __shared__ int sidx[ET_];
    __shared__ float sw[ET_];
    __shared__ float r0[4], r1[4];
    if (tid < ET_) {
        sidx[tid] = indices[c * ET_ + tid];
        sw[tid] = wbuf[t * ET_ + tid];
    }
    float4 xv = ((const float4*)(xf + (size_t)t * D_))[tid];
    float acc[4] = {0.f, 0.f, 0.f, 0.f};
    __syncthreads();
    for (int e = 0; e < ET_; e++) {
        int idx = sidx[e];
        size_t base = (size_t)idx * D_;
        float4 w0 = *(const float4*)(experts + base + tid * 4);
        float4 w1 = *(const float4*)(experts + (size_t)E_ * D_ + base + tid * 4);
        float p0 = xv.x * w0.x + xv.y * w0.y + xv.z * w0.z + xv.w * w0.w;
        float p1 = xv.x * w1.x + xv.y * w1.y + xv.z * w1.z + xv.w * w1.w;
#pragma unroll
        for (int off = 32; off > 0; off >>= 1) {
            p0 += __shfl_xor(p0, off);
            p1 += __shfl_xor(p1, off);
        }
        if ((tid & 63) == 0) { r0[tid >> 6] = p0; r1[tid >> 6] = p1; }
        __syncthreads();
        float h0 = r0[0] + r0[1] + r0[2] + r0[3];
        float h1 = r1[0] + r1[1] + r1[2] + r1[3];
        __syncthreads();   // protect r0/r1 reuse next iteration
        float act = h0 / (1.0f + __expf(-h0)) * h1 * sw[e];  // silu(h0)*h1*w
        float4 w2 = *(const float4*)(experts + (size_t)2 * E_ * D_ + base + tid * 4);
        acc[0] += act * w2.x;
        acc[1] += act * w2.y;
        acc[2] += act * w2.z;
        acc[3] += act * w2.w;
    }
    size_t o = (size_t)t * D_ + tid * 4;
    float4 rv = *(const float4*)(xfi + o);
    float4 ov;
    ov.x = acc[0] + rv.x;
    ov.y = acc[1] + rv.y;
    ov.z = acc[2] + rv.z;
    ov.w = acc[3] + rv.w;
    *(float4*)(out + o) = ov;
}

// ---------------------------------------------------------------------------
extern "C" void kernel_launch(void* const* d_in, const int* in_sizes, int n_in,
                              void* d_out, int out_size, void* d_ws, size_t ws_size,
                              hipStream_t stream)
{
    (void)in_sizes; (void)n_in; (void)out_size; (void)ws_size;
    const float* x_input     = (const float*)d_in[0];
    const int*   indices     = (const int*)d_in[1];
    const float* scores      = (const float*)d_in[2];
    const float* attn_w      = (const float*)d_in[3];
    const float* attn_out_w  = (const float*)d_in[4];
    const float* attn_norm_w = (const float*)d_in[5];
    const float* ffn_norm_w  = (const float*)d_in[6];
    const float* ffn_experts = (const float*)d_in[7];
    const float* keys        = (const float*)d_in[8];
    const float* head_probs  = (const float*)d_in[9];
    const float* score_probs = (const float*)d_in[10];
    float* out = (float*)d_out;

    float* ws = (float*)d_ws;
    const size_t MF = 1024 * 1024;
    // Region map (floats), peak 12M floats = 48 MB:
    //   [0,2M)=A  [2M,8M)=B  [8M,10M)=C  [10M,12M)=D
    float* xn   = ws + 8 * MF;    // C: rmsnorm(x)
    float* qkv  = ws + 2 * MF;    // B[0..6M): T x 3D
    float* qh   = ws + 8 * MF;    // C (xn dead after gemm1)
    float* khb  = ws;             // A
    float* vhb  = ws + 10 * MF;   // D
    float* ao   = ws + 2 * MF;    // B[0..2M) (qkv dead after prep)
    float* xfi  = ws + 4 * MF;    // B[2..4M)
    float* xf   = ws + 6 * MF;    // B[4..6M)
    float* wbuf = ws;             // A (khb dead after attn)

    rmsnorm_kernel<<<T_, 256, 0, stream>>>(x_input, attn_norm_w, xn);

    dim3 g1(3 * D_ / BN, T_ / BM);
    gemm_kernel<<<g1, 256, 0, stream>>>(xn, attn_w, nullptr, qkv, T_, 3 * D_, D_);

    qkv_prep_kernel<<<T_ * NH_, 64, 0, stream>>>(qkv, qh, khb, vhb);

    flash_attn_kernel<<<NH_ * 16, 256, 0, stream>>>(qh, khb, vhb, ao);

    dim3 g2(D_ / BN, T_ / BM);
    gemm_kernel<<<g2, 256, 0, stream>>>(ao, attn_out_w, x_input, xfi, T_, D_, D_);

    rmsnorm_kernel<<<T_, 256, 0, stream>>>(xfi, ffn_norm_w, xf);

    expert_score_kernel<<<BC_ * ET_, 256, 0, stream>>>(
        xf, keys, scores, head_probs, score_probs, indices, wbuf);

    moe_kernel<<<T_, 256, 0, stream>>>(xf, xfi, indices, wbuf, ffn_experts, out);
}

// Round 4
// 696.179 us; speedup vs baseline: 6.6208x; 1.3636x over previous
//
#include <hip/hip_runtime.h>
#include <hip/hip_bf16.h>
#include <math.h>

// Problem constants
#define D_   1024
#define HD_  64
#define NH_  16
#define H_   16
#define KH_  8
#define NT_  128      // tokens per chunk (N)
#define E_   4096
#define RE_  4
#define DE_  4
#define ET_  16
#define S_   2048
#define T_   2048
#define BC_  16
#define EPS_ 1e-5f

typedef short s16x8 __attribute__((ext_vector_type(8)));
typedef float f32x4 __attribute__((ext_vector_type(4)));

__device__ __forceinline__ unsigned short f2bf(float f) {
    union { float f; unsigned int u; } v; v.f = f;
    unsigned int r = (v.u + 0x7fffu + ((v.u >> 16) & 1u)) >> 16;  // RNE
    return (unsigned short)r;
}

// ---------------------------------------------------------------------------
// rmsnorm (fp32 out)
// ---------------------------------------------------------------------------
__global__ __launch_bounds__(256) void rmsnorm_kernel(
    const float* __restrict__ x, const float* __restrict__ w,
    float* __restrict__ out)
{
    int row = blockIdx.x, tid = threadIdx.x;
    __shared__ float sred[4];
    float4 v = ((const float4*)(x + (size_t)row * D_))[tid];
    float ss = v.x*v.x + v.y*v.y + v.z*v.z + v.w*v.w;
#pragma unroll
    for (int off = 32; off > 0; off >>= 1) ss += __shfl_xor(ss, off);
    if ((tid & 63) == 0) sred[tid >> 6] = ss;
    __syncthreads();
    float tot = sred[0] + sred[1] + sred[2] + sred[3];
    float scale = rsqrtf(tot * (1.0f / D_) + EPS_);
    float4 wv = ((const float4*)w)[tid];
    float4 o;
    o.x = v.x * scale * wv.x;
    o.y = v.y * scale * wv.y;
    o.z = v.z * scale * wv.z;
    o.w = v.w * scale * wv.w;
    ((float4*)(out + (size_t)row * D_))[tid] = o;
}

// rmsnorm (bf16 out)
__global__ __launch_bounds__(256) void rmsnorm_bf16_kernel(
    const float* __restrict__ x, const float* __restrict__ w,
    unsigned short* __restrict__ out)
{
    int row = blockIdx.x, tid = threadIdx.x;
    __shared__ float sred[4];
    float4 v = ((const float4*)(x + (size_t)row * D_))[tid];
    float ss = v.x*v.x + v.y*v.y + v.z*v.z + v.w*v.w;
#pragma unroll
    for (int off = 32; off > 0; off >>= 1) ss += __shfl_xor(ss, off);
    if ((tid & 63) == 0) sred[tid >> 6] = ss;
    __syncthreads();
    float tot = sred[0] + sred[1] + sred[2] + sred[3];
    float scale = rsqrtf(tot * (1.0f / D_) + EPS_);
    float4 wv = ((const float4*)w)[tid];
    ushort4 o;
    o.x = f2bf(v.x * scale * wv.x);
    o.y = f2bf(v.y * scale * wv.y);
    o.z = f2bf(v.z * scale * wv.z);
    o.w = f2bf(v.w * scale * wv.w);
    *(ushort4*)(out + (size_t)row * D_ + tid * 4) = o;
}

// ---------------------------------------------------------------------------
// convert + transpose: src [R][Ncols] fp32  ->  dst [Ncols][R] bf16
// ---------------------------------------------------------------------------
__global__ __launch_bounds__(256) void convt_kernel(
    const float* __restrict__ src, unsigned short* __restrict__ dst,
    int R, int Ncols)
{
    __shared__ float tile[32][33];
    int bx = blockIdx.x * 32;   // col block
    int by = blockIdx.y * 32;   // row block
    int tx = threadIdx.x & 31, ty = threadIdx.x >> 5;  // 8 rows per pass
#pragma unroll
    for (int rr = 0; rr < 32; rr += 8)
        tile[ty + rr][tx] = src[(size_t)(by + ty + rr) * Ncols + bx + tx];
    __syncthreads();
#pragma unroll
    for (int rr = 0; rr < 32; rr += 8)
        dst[(size_t)(bx + ty + rr) * R + by + tx] = f2bf(tile[tx][ty + rr]);
}

// ---------------------------------------------------------------------------
// MFMA GEMM: C[M,N] fp32 = A[M,K] bf16 @ Bt[N,K] bf16 (+ res fp32)
// 128x128 tile, BK=32, 256 thr = 4 waves, each wave a 64x64 quadrant as
// 4x4 grid of mfma_f32_16x16x32_bf16 accumulators.
// ---------------------------------------------------------------------------
template <int WITH_RES>
__global__ __launch_bounds__(256) void mfma_gemm_kernel(
    const unsigned short* __restrict__ A, const unsigned short* __restrict__ Bt,
    const float* __restrict__ res, float* __restrict__ C,
    int M, int N, int K)
{
    __shared__ short As[128][40];   // padded: rows 80 B (16B-aligned)
    __shared__ short Bs[128][40];
    int tid = threadIdx.x;
    int wave = tid >> 6, lane = tid & 63;
    int ml = lane & 15, q = lane >> 4;
    int wr = wave >> 1, wc = wave & 1;
    int bm = blockIdx.y * 128, bn = blockIdx.x * 128;
    int srow = tid >> 2;          // 0..63
    int scol = (tid & 3) * 8;     // k element offset

    f32x4 acc[4][4];
#pragma unroll
    for (int i = 0; i < 4; i++)
#pragma unroll
        for (int j = 0; j < 4; j++) acc[i][j] = (f32x4){0.f, 0.f, 0.f, 0.f};

    for (int k0 = 0; k0 < K; k0 += 32) {
        // stage A,B tiles (each thread: 2 rows x 8 bf16 per matrix)
        int4 a0 = *(const int4*)(A + (size_t)(bm + srow) * K + k0 + scol);
        int4 a1 = *(const int4*)(A + (size_t)(bm + srow + 64) * K + k0 + scol);
        int4 b0 = *(const int4*)(Bt + (size_t)(bn + srow) * K + k0 + scol);
        int4 b1 = *(const int4*)(Bt + (size_t)(bn + srow + 64) * K + k0 + scol);
        __syncthreads();
        *(int4*)(&As[srow][scol]) = a0;
        *(int4*)(&As[srow + 64][scol]) = a1;
        *(int4*)(&Bs[srow][scol]) = b0;
        *(int4*)(&Bs[srow + 64][scol]) = b1;
        __syncthreads();

        s16x8 af[4], bf[4];
#pragma unroll
        for (int i = 0; i < 4; i++)
            af[i] = *(const s16x8*)(&As[wr * 64 + i * 16 + ml][q * 8]);
#pragma unroll
        for (int j = 0; j < 4; j++)
            bf[j] = *(const s16x8*)(&Bs[wc * 64 + j * 16 + ml][q * 8]);
#pragma unroll
        for (int i = 0; i < 4; i++)
#pragma unroll
            for (int j = 0; j < 4; j++)
                acc[i][j] = __builtin_amdgcn_mfma_f32_16x16x32_bf16(
                    af[i], bf[j], acc[i][j], 0, 0, 0);
    }

    // epilogue: C[row= q*4+r][col= ml] per 16x16 block
#pragma unroll
    for (int i = 0; i < 4; i++) {
#pragma unroll
        for (int j = 0; j < 4; j++) {
            int col = bn + wc * 64 + j * 16 + ml;
#pragma unroll
            for (int r = 0; r < 4; r++) {
                int row = bm + wr * 64 + i * 16 + q * 4 + r;
                float v = acc[i][j][r];
                if (WITH_RES) v += res[(size_t)row * N + col];
                C[(size_t)row * N + col] = v;
            }
        }
    }
}

// ---------------------------------------------------------------------------
// qkv prep: split qkv rows into per-head (NH,S,HD) q/k/v with l2norm + rope
// ---------------------------------------------------------------------------
__global__ __launch_bounds__(64) void qkv_prep_kernel(
    const float* __restrict__ qkv, float* __restrict__ qh,
    float* __restrict__ khb, float* __restrict__ vhb)
{
    int bid = blockIdx.x;
    int s = bid / NH_, h = bid % NH_;
    int lane = threadIdx.x;

    size_t qoff = (size_t)s * (3 * D_) + h * HD_ + lane;
    float qv = qkv[qoff];
    float kv = qkv[qoff + D_];
    float vv = qkv[qoff + 2 * D_];

    float sq = qv * qv, sk = kv * kv;
#pragma unroll
    for (int off = 32; off > 0; off >>= 1) {
        sq += __shfl_xor(sq, off);
        sk += __shfl_xor(sk, off);
    }
    qv /= fmaxf(sqrtf(sq), EPS_);
    kv /= fmaxf(sqrtf(sk), EPS_);

    int j = lane & 31;
    float sign = (lane < 32) ? 1.0f : -1.0f;
    float inv_freq = exp2f((float)j * (-13.287712379549449f / 32.0f));
    float f = (float)s * inv_freq;
    float sn, cs;
    sincosf(f, &sn, &cs);
    float qo = __shfl_xor(qv, 32);
    float ko = __shfl_xor(kv, 32);
    qv = qv * cs + sign * qo * sn;
    kv = kv * cs + sign * ko * sn;

    size_t o = ((size_t)h * S_ + s) * HD_ + lane;
    qh[o] = qv;
    khb[o] = kv;
    vhb[o] = vv;
}

// ---------------------------------------------------------------------------
// Tiled causal flash attention (fp32 compute, bf16 output).
// ---------------------------------------------------------------------------
#define NQT_ (S_ / 64)   // 32 q-tiles per head
__global__ __launch_bounds__(256) void flash_attn_kernel(
    const float* __restrict__ qh, const float* __restrict__ khb,
    const float* __restrict__ vhb, unsigned short* __restrict__ aob)
{
    __shared__ float Qs[64][65];
    __shared__ float Ks[64][65];
    __shared__ float Vs[64][68];
    __shared__ float Ps[64][68];
    int h = blockIdx.x >> 4;
    int p = blockIdx.x & 15;
    int tid = threadIdx.x;
    int ty = tid >> 4, tx = tid & 15;
    const float* Qb = qh  + (size_t)h * S_ * HD_;
    const float* Kb = khb + (size_t)h * S_ * HD_;
    const float* Vb = vhb + (size_t)h * S_ * HD_;

    for (int half = 0; half < 2; half++) {
        int t = half ? (NQT_ - 1 - p) : p;
        int q0 = t * 64;

#pragma unroll
        for (int rr = 0; rr < 4; rr++) {
            int r = ty + 16 * rr;
            float4 qv4 = *(const float4*)(Qb + (size_t)(q0 + r) * HD_ + 4 * tx);
            Qs[4 * tx + 0][r] = qv4.x * 0.125f;
            Qs[4 * tx + 1][r] = qv4.y * 0.125f;
            Qs[4 * tx + 2][r] = qv4.z * 0.125f;
            Qs[4 * tx + 3][r] = qv4.w * 0.125f;
        }

        float m[4], l[4], accO[4][4];
#pragma unroll
        for (int i = 0; i < 4; i++) {
            m[i] = -INFINITY; l[i] = 0.f;
#pragma unroll
            for (int j = 0; j < 4; j++) accO[i][j] = 0.f;
        }

        for (int kt = 0; kt <= t; kt++) {
            int k0 = kt * 64;
#pragma unroll
            for (int rr = 0; rr < 4; rr++) {
                int r = ty + 16 * rr;
                float4 kv4 = *(const float4*)(Kb + (size_t)(k0 + r) * HD_ + 4 * tx);
                Ks[4 * tx + 0][r] = kv4.x;
                Ks[4 * tx + 1][r] = kv4.y;
                Ks[4 * tx + 2][r] = kv4.z;
                Ks[4 * tx + 3][r] = kv4.w;
                float4 vv4 = *(const float4*)(Vb + (size_t)(k0 + r) * HD_ + 4 * tx);
                *(float4*)(&Vs[r][4 * tx]) = vv4;
            }
            __syncthreads();

            float acc[4][4];
#pragma unroll
            for (int i = 0; i < 4; i++)
#pragma unroll
                for (int j = 0; j < 4; j++) acc[i][j] = 0.f;
#pragma unroll 8
            for (int d = 0; d < 64; d++) {
                float av[4], bv[4];
#pragma unroll
                for (int i = 0; i < 4; i++) av[i] = Qs[d][4 * ty + i];
#pragma unroll
                for (int j = 0; j < 4; j++) bv[j] = Ks[d][4 * tx + j];
#pragma unroll
                for (int i = 0; i < 4; i++)
#pragma unroll
                    for (int j = 0; j < 4; j++)
                        acc[i][j] += av[i] * bv[j];
            }

            if (kt == t) {
#pragma unroll
                for (int i = 0; i < 4; i++)
#pragma unroll
                    for (int j = 0; j < 4; j++)
                        if (4 * tx + j > 4 * ty + i) acc[i][j] = -1e30f;
            }

            float pp[4][4];
#pragma unroll
            for (int i = 0; i < 4; i++) {
                float mt = fmaxf(fmaxf(acc[i][0], acc[i][1]),
                                 fmaxf(acc[i][2], acc[i][3]));
#pragma unroll
                for (int off = 1; off < 16; off <<= 1)
                    mt = fmaxf(mt, __shfl_xor(mt, off));
                float mn = fmaxf(m[i], mt);
                float corr = __expf(m[i] - mn);
                m[i] = mn;
                float rs = 0.f;
#pragma unroll
                for (int j = 0; j < 4; j++) {
                    float pv = __expf(acc[i][j] - mn);
                    pp[i][j] = pv;
                    rs += pv;
                }
#pragma unroll
                for (int off = 1; off < 16; off <<= 1)
                    rs += __shfl_xor(rs, off);
                l[i] = l[i] * corr + rs;
#pragma unroll
                for (int j = 0; j < 4; j++) accO[i][j] *= corr;
            }

#pragma unroll
            for (int i = 0; i < 4; i++) {
                float4 pv4 = make_float4(pp[i][0], pp[i][1], pp[i][2], pp[i][3]);
                *(float4*)(&Ps[4 * ty + i][4 * tx]) = pv4;
            }
            __syncthreads();

#pragma unroll 8
            for (int j = 0; j < 64; j++) {
                float4 bv4 = *(const float4*)(&Vs[j][4 * tx]);
#pragma unroll
                for (int i = 0; i < 4; i++) {
                    float pv = Ps[4 * ty + i][j];
                    accO[i][0] += pv * bv4.x;
                    accO[i][1] += pv * bv4.y;
                    accO[i][2] += pv * bv4.z;
                    accO[i][3] += pv * bv4.w;
                }
            }
            __syncthreads();
        }

        // epilogue: normalize, convert bf16, store to (T, D)
#pragma unroll
        for (int i = 0; i < 4; i++) {
            float inv = 1.0f / l[i];
            ushort4 ov;
            ov.x = f2bf(accO[i][0] * inv);
            ov.y = f2bf(accO[i][1] * inv);
            ov.z = f2bf(accO[i][2] * inv);
            ov.w = f2bf(accO[i][3] * inv);
            *(ushort4*)(aob + (size_t)(q0 + 4 * ty + i) * D_ + h * HD_ + 4 * tx) = ov;
        }
        __syncthreads();
    }
}

// ---------------------------------------------------------------------------
// expert scores + combine weights. One block per (chunk c, expert slot e).
// ---------------------------------------------------------------------------
__global__ __launch_bounds__(256) void expert_score_kernel(
    const float* __restrict__ xf, const float* __restrict__ keys,
    const float* __restrict__ scores,
    const float* __restrict__ head_probs,
    const float* __restrict__ score_probs,
    const int* __restrict__ indices, float* __restrict__ wbuf)
{
    __shared__ float Ks[KH_][D_];
    __shared__ float Xs[NT_][33];
    __shared__ float Ds[NT_][9];
    __shared__ float sp0[H_], sp1[H_], hp[H_];
    int blk = blockIdx.x;
    int c = blk / ET_, e = blk % ET_;
    int tid = threadIdx.x;
    int idx = indices[c * ET_ + e];
    int r = e / DE_;
    for (int i = tid; i < KH_ * D_; i += 256) {
        int kh = i >> 10, d = i & 1023;
        Ks[kh][d] = keys[((size_t)kh * D_ + d) * E_ + idx];
    }
    if (tid < H_) {
        int h = tid;
        sp0[h] = score_probs[((size_t)(0 * RE_ + r) * E_ + idx) * H_ + h];
        sp1[h] = score_probs[((size_t)(1 * RE_ + r) * E_ + idx) * H_ + h];
        hp[h]  = head_probs[((size_t)r * E_ + idx) * H_ + h];
    }
    float acc[4] = {0.f, 0.f, 0.f, 0.f};
    int tl = tid & 127;
    int g = tid >> 7;
    for (int d0 = 0; d0 < D_; d0 += 32) {
        __syncthreads();
        for (int i = tid; i < NT_ * 32; i += 256) {
            int t = i >> 5, d = i & 31;
            Xs[t][d] = xf[((size_t)(c * NT_ + t)) * D_ + d0 + d];
        }
        __syncthreads();
        for (int d = 0; d < 32; d++) {
            float aval = Xs[tl][d];
#pragma unroll
            for (int j = 0; j < 4; j++)
                acc[j] += aval * Ks[g * 4 + j][d0 + d];
        }
    }
    __syncthreads();
#pragma unroll
    for (int j = 0; j < 4; j++) Ds[tl][g * 4 + j] = acc[j];
    __syncthreads();
    if (tid < NT_) {
        int t = c * NT_ + tid;
        float wsum = 0.f;
#pragma unroll
        for (int h = 0; h < H_; h++) {
            float mval = Ds[tid][h >> 1];
            float sc = scores[((size_t)t * ET_ + e) * H_ + h];
            float z = sp0[h] * mval + sp1[h] * sc;
            float cmb = 1.0f / (1.0f + __expf(-z));
            wsum += cmb * hp[h];
        }
        wbuf[t * ET_ + e] = wsum;
    }
}

// ---------------------------------------------------------------------------
// MoE with rank-1 experts. One block per token.
// ---------------------------------------------------------------------------
__global__ __launch_bounds__(256) void moe_kernel(
    const float* __restrict__ xf, const float* __restrict__ xfi,
    const int* __restrict__ indices, const float* __restrict__ wbuf,
    const float* __restrict__ experts, float* __restrict__ out)
{
    int t = blockIdx.x, tid = threadIdx.x;
    int c = t / NT_;
    __shared__ int sidx[ET_];
    __shared__ float sw[ET_];
    __shared__ float r0[4], r1[4];
    if (tid < ET_) {
        sidx[tid] = indices[c * ET_ + tid];
        sw[tid] = wbuf[t * ET_ + tid];
    }
    float4 xv = ((const float4*)(xf + (size_t)t * D_))[tid];
    float acc[4] = {0.f, 0.f, 0.f, 0.f};
    __syncthreads();
    for (int e = 0; e < ET_; e++) {
        int idx = sidx[e];
        size_t base = (size_t)idx * D_;
        float4 w0 = *(const float4*)(experts + base + tid * 4);
        float4 w1 = *(const float4*)(experts + (size_t)E_ * D_ + base + tid * 4);
        float p0 = xv.x * w0.x + xv.y * w0.y + xv.z * w0.z + xv.w * w0.w;
        float p1 = xv.x * w1.x + xv.y * w1.y + xv.z * w1.z + xv.w * w1.w;
#pragma unroll
        for (int off = 32; off > 0; off >>= 1) {
            p0 += __shfl_xor(p0, off);
            p1 += __shfl_xor(p1, off);
        }
        if ((tid & 63) == 0) { r0[tid >> 6] = p0; r1[tid >> 6] = p1; }
        __syncthreads();
        float h0 = r0[0] + r0[1] + r0[2] + r0[3];
        float h1 = r1[0] + r1[1] + r1[2] + r1[3];
        __syncthreads();
        float act = h0 / (1.0f + __expf(-h0)) * h1 * sw[e];
        float4 w2 = *(const float4*)(experts + (size_t)2 * E_ * D_ + base + tid * 4);
        acc[0] += act * w2.x;
        acc[1] += act * w2.y;
        acc[2] += act * w2.z;
        acc[3] += act * w2.w;
    }
    size_t o = (size_t)t * D_ + tid * 4;
    float4 rv = *(const float4*)(xfi + o);
    float4 ov;
    ov.x = acc[0] + rv.x;
    ov.y = acc[1] + rv.y;
    ov.z = acc[2] + rv.z;
    ov.w = acc[3] + rv.w;
    *(float4*)(out + o) = ov;
}

// ---------------------------------------------------------------------------
extern "C" void kernel_launch(void* const* d_in, const int* in_sizes, int n_in,
                              void* d_out, int out_size, void* d_ws, size_t ws_size,
                              hipStream_t stream)
{
    (void)in_sizes; (void)n_in; (void)out_size; (void)ws_size;
    const float* x_input     = (const float*)d_in[0];
    const int*   indices     = (const int*)d_in[1];
    const float* scores      = (const float*)d_in[2];
    const float* attn_w      = (const float*)d_in[3];
    const float* attn_out_w  = (const float*)d_in[4];
    const float* attn_norm_w = (const float*)d_in[5];
    const float* ffn_norm_w  = (const float*)d_in[6];
    const float* ffn_experts = (const float*)d_in[7];
    const float* keys        = (const float*)d_in[8];
    const float* head_probs  = (const float*)d_in[9];
    const float* score_probs = (const float*)d_in[10];
    float* out = (float*)d_out;

    float* ws = (float*)d_ws;
    const size_t MF = 1024 * 1024;
    // Region map (floats), peak 12M floats = 48 MB:
    // A [0,6M): qkv (gemm1 out); after qkv_prep reused as:
    //    aob [0,1M) bf16 | xfi [1M,3M) | xf [3M,5M) | wbuf [5M,5M+32K) | woutT [5.5M,6M) bf16
    // B [6M,8M): xnb bf16 (steps 1-3) -> qh (step 4+)
    // C [8M,10M): wqkvT bf16 (steps 2-3, 1.5M floats) -> khb (step 4+)
    // D [10M,12M): vhb
    float* qkv            = ws;
    unsigned short* aob   = (unsigned short*)ws;
    float* xfi            = ws + 1 * MF;
    float* xf             = ws + 3 * MF;
    float* wbuf           = ws + 5 * MF;
    unsigned short* woutT = (unsigned short*)(ws + 5 * MF + 512 * 1024);
    unsigned short* xnb   = (unsigned short*)(ws + 6 * MF);
    float* qh             = ws + 6 * MF;
    unsigned short* wqkvT = (unsigned short*)(ws + 8 * MF);
    float* khb            = ws + 8 * MF;
    float* vhb            = ws + 10 * MF;

    // 1) rmsnorm -> bf16 A
    rmsnorm_bf16_kernel<<<T_, 256, 0, stream>>>(x_input, attn_norm_w, xnb);

    // 2) attn_w (1024 x 3072) -> wqkvT [3072][1024] bf16
    {
        dim3 g(3 * D_ / 32, D_ / 32);
        convt_kernel<<<g, 256, 0, stream>>>(attn_w, wqkvT, D_, 3 * D_);
    }

    // 3) qkv = xnb @ attn_w   (MFMA)
    {
        dim3 g(3 * D_ / 128, T_ / 128);
        mfma_gemm_kernel<0><<<g, 256, 0, stream>>>(xnb, wqkvT, nullptr, qkv,
                                                   T_, 3 * D_, D_);
    }

    // 4) split + l2norm + rope
    qkv_prep_kernel<<<T_ * NH_, 64, 0, stream>>>(qkv, qh, khb, vhb);

    // 5) flash attention -> aob bf16
    flash_attn_kernel<<<NH_ * 16, 256, 0, stream>>>(qh, khb, vhb, aob);

    // 6) attn_out_w (1024 x 1024) -> woutT [1024][1024] bf16
    {
        dim3 g(D_ / 32, D_ / 32);
        convt_kernel<<<g, 256, 0, stream>>>(attn_out_w, woutT, D_, D_);
    }

    // 7) xfi = aob @ attn_out_w + x_input   (MFMA + residual)
    {
        dim3 g(D_ / 128, T_ / 128);
        mfma_gemm_kernel<1><<<g, 256, 0, stream>>>(aob, woutT, x_input, xfi,
                                                   T_, D_, D_);
    }

    // 8) rmsnorm fp32
    rmsnorm_kernel<<<T_, 256, 0, stream>>>(xfi, ffn_norm_w, xf);

    // 9) expert scores -> combine weights
    expert_score_kernel<<<BC_ * ET_, 256, 0, stream>>>(
        xf, keys, scores, head_probs, score_probs, indices, wbuf);

    // 10) MoE + final residual
    moe_kernel<<<T_, 256, 0, stream>>>(xf, xfi, indices, wbuf, ffn_experts, out);
}

// Round 5
// 537.111 us; speedup vs baseline: 8.5816x; 1.2962x over previous
//
#include <hip/hip_runtime.h>
#include <hip/hip_bf16.h>
#include <math.h>

// Problem constants
#define D_   1024
#define HD_  64
#define NH_  16
#define H_   16
#define KH_  8
#define NT_  128      // tokens per chunk (N)
#define E_   4096
#define RE_  4
#define DE_  4
#define ET_  16
#define S_   2048
#define T_   2048
#define BC_  16
#define EPS_ 1e-5f

typedef short s16x8 __attribute__((ext_vector_type(8)));
typedef float f32x4 __attribute__((ext_vector_type(4)));

__device__ __forceinline__ unsigned short f2bf(float f) {
    union { float f; unsigned int u; } v; v.f = f;
    unsigned int r = (v.u + 0x7fffu + ((v.u >> 16) & 1u)) >> 16;  // RNE
    return (unsigned short)r;
}

// ---------------------------------------------------------------------------
// rmsnorm (fp32 out)
// ---------------------------------------------------------------------------
__global__ __launch_bounds__(256) void rmsnorm_kernel(
    const float* __restrict__ x, const float* __restrict__ w,
    float* __restrict__ out)
{
    int row = blockIdx.x, tid = threadIdx.x;
    __shared__ float sred[4];
    float4 v = ((const float4*)(x + (size_t)row * D_))[tid];
    float ss = v.x*v.x + v.y*v.y + v.z*v.z + v.w*v.w;
#pragma unroll
    for (int off = 32; off > 0; off >>= 1) ss += __shfl_xor(ss, off);
    if ((tid & 63) == 0) sred[tid >> 6] = ss;
    __syncthreads();
    float tot = sred[0] + sred[1] + sred[2] + sred[3];
    float scale = rsqrtf(tot * (1.0f / D_) + EPS_);
    float4 wv = ((const float4*)w)[tid];
    float4 o;
    o.x = v.x * scale * wv.x;
    o.y = v.y * scale * wv.y;
    o.z = v.z * scale * wv.z;
    o.w = v.w * scale * wv.w;
    ((float4*)(out + (size_t)row * D_))[tid] = o;
}

// rmsnorm (bf16 out)
__global__ __launch_bounds__(256) void rmsnorm_bf16_kernel(
    const float* __restrict__ x, const float* __restrict__ w,
    unsigned short* __restrict__ out)
{
    int row = blockIdx.x, tid = threadIdx.x;
    __shared__ float sred[4];
    float4 v = ((const float4*)(x + (size_t)row * D_))[tid];
    float ss = v.x*v.x + v.y*v.y + v.z*v.z + v.w*v.w;
#pragma unroll
    for (int off = 32; off > 0; off >>= 1) ss += __shfl_xor(ss, off);
    if ((tid & 63) == 0) sred[tid >> 6] = ss;
    __syncthreads();
    float tot = sred[0] + sred[1] + sred[2] + sred[3];
    float scale = rsqrtf(tot * (1.0f / D_) + EPS_);
    float4 wv = ((const float4*)w)[tid];
    ushort4 o;
    o.x = f2bf(v.x * scale * wv.x);
    o.y = f2bf(v.y * scale * wv.y);
    o.z = f2bf(v.z * scale * wv.z);
    o.w = f2bf(v.w * scale * wv.w);
    *(ushort4*)(out + (size_t)row * D_ + tid * 4) = o;
}

// ---------------------------------------------------------------------------
// convert + transpose: src [R][Ncols] fp32  ->  dst [Ncols][R] bf16
// ---------------------------------------------------------------------------
__global__ __launch_bounds__(256) void convt_kernel(
    const float* __restrict__ src, unsigned short* __restrict__ dst,
    int R, int Ncols)
{
    __shared__ float tile[32][33];
    int bx = blockIdx.x * 32;   // col block
    int by = blockIdx.y * 32;   // row block
    int tx = threadIdx.x & 31, ty = threadIdx.x >> 5;  // 8 rows per pass
#pragma unroll
    for (int rr = 0; rr < 32; rr += 8)
        tile[ty + rr][tx] = src[(size_t)(by + ty + rr) * Ncols + bx + tx];
    __syncthreads();
#pragma unroll
    for (int rr = 0; rr < 32; rr += 8)
        dst[(size_t)(bx + ty + rr) * R + by + tx] = f2bf(tile[tx][ty + rr]);
}

// ---------------------------------------------------------------------------
// MFMA GEMM: C[M,N] fp32 = A[M,K] bf16 @ Bt[N,K] bf16 (+ res fp32)
// ---------------------------------------------------------------------------
template <int WITH_RES>
__global__ __launch_bounds__(256) void mfma_gemm_kernel(
    const unsigned short* __restrict__ A, const unsigned short* __restrict__ Bt,
    const float* __restrict__ res, float* __restrict__ C,
    int M, int N, int K)
{
    __shared__ short As[128][40];
    __shared__ short Bs[128][40];
    int tid = threadIdx.x;
    int wave = tid >> 6, lane = tid & 63;
    int ml = lane & 15, q = lane >> 4;
    int wr = wave >> 1, wc = wave & 1;
    int bm = blockIdx.y * 128, bn = blockIdx.x * 128;
    int srow = tid >> 2;
    int scol = (tid & 3) * 8;

    f32x4 acc[4][4];
#pragma unroll
    for (int i = 0; i < 4; i++)
#pragma unroll
        for (int j = 0; j < 4; j++) acc[i][j] = (f32x4){0.f, 0.f, 0.f, 0.f};

    for (int k0 = 0; k0 < K; k0 += 32) {
        int4 a0 = *(const int4*)(A + (size_t)(bm + srow) * K + k0 + scol);
        int4 a1 = *(const int4*)(A + (size_t)(bm + srow + 64) * K + k0 + scol);
        int4 b0 = *(const int4*)(Bt + (size_t)(bn + srow) * K + k0 + scol);
        int4 b1 = *(const int4*)(Bt + (size_t)(bn + srow + 64) * K + k0 + scol);
        __syncthreads();
        *(int4*)(&As[srow][scol]) = a0;
        *(int4*)(&As[srow + 64][scol]) = a1;
        *(int4*)(&Bs[srow][scol]) = b0;
        *(int4*)(&Bs[srow + 64][scol]) = b1;
        __syncthreads();

        s16x8 af[4], bf[4];
#pragma unroll
        for (int i = 0; i < 4; i++)
            af[i] = *(const s16x8*)(&As[wr * 64 + i * 16 + ml][q * 8]);
#pragma unroll
        for (int j = 0; j < 4; j++)
            bf[j] = *(const s16x8*)(&Bs[wc * 64 + j * 16 + ml][q * 8]);
#pragma unroll
        for (int i = 0; i < 4; i++)
#pragma unroll
            for (int j = 0; j < 4; j++)
                acc[i][j] = __builtin_amdgcn_mfma_f32_16x16x32_bf16(
                    af[i], bf[j], acc[i][j], 0, 0, 0);
    }

#pragma unroll
    for (int i = 0; i < 4; i++) {
#pragma unroll
        for (int j = 0; j < 4; j++) {
            int col = bn + wc * 64 + j * 16 + ml;
#pragma unroll
            for (int r = 0; r < 4; r++) {
                int row = bm + wr * 64 + i * 16 + q * 4 + r;
                float v = acc[i][j][r];
                if (WITH_RES) v += res[(size_t)row * N + col];
                C[(size_t)row * N + col] = v;
            }
        }
    }
}

// ---------------------------------------------------------------------------
// qkv prep: split qkv into per-head (NH,S,HD) bf16 q/k/v with l2norm + rope.
// q is pre-scaled by 1/sqrt(HD).
// ---------------------------------------------------------------------------
__global__ __launch_bounds__(64) void qkv_prep_kernel(
    const float* __restrict__ qkv, unsigned short* __restrict__ qh,
    unsigned short* __restrict__ khb, unsigned short* __restrict__ vhb)
{
    int bid = blockIdx.x;
    int s = bid / NH_, h = bid % NH_;
    int lane = threadIdx.x;

    size_t qoff = (size_t)s * (3 * D_) + h * HD_ + lane;
    float qv = qkv[qoff];
    float kv = qkv[qoff + D_];
    float vv = qkv[qoff + 2 * D_];

    float sq = qv * qv, sk = kv * kv;
#pragma unroll
    for (int off = 32; off > 0; off >>= 1) {
        sq += __shfl_xor(sq, off);
        sk += __shfl_xor(sk, off);
    }
    qv /= fmaxf(sqrtf(sq), EPS_);
    kv /= fmaxf(sqrtf(sk), EPS_);

    int j = lane & 31;
    float sign = (lane < 32) ? 1.0f : -1.0f;
    float inv_freq = exp2f((float)j * (-13.287712379549449f / 32.0f));
    float f = (float)s * inv_freq;
    float sn, cs;
    sincosf(f, &sn, &cs);
    float qo = __shfl_xor(qv, 32);
    float ko = __shfl_xor(kv, 32);
    qv = qv * cs + sign * qo * sn;
    kv = kv * cs + sign * ko * sn;

    size_t o = ((size_t)h * S_ + s) * HD_ + lane;
    qh[o]  = f2bf(qv * 0.125f);   // fold 1/sqrt(64)
    khb[o] = f2bf(kv);
    vhb[o] = f2bf(vv);
}

// ---------------------------------------------------------------------------
// MFMA bf16 flash attention. Block = 256 thr = 4 waves; each wave owns 16
// q-rows of a 64-row q-tile. Paired q-tiles (t, 31-t): every block runs
// exactly 33 k-tile iterations. Per k-tile: QK^T (8 mfma 16x16x32), online
// softmax in C-layout regs, P->LDS bf16, PV (8 mfma, V transposed in LDS).
// LDS: 4 x 64x72 shorts = 36 KB.
// ---------------------------------------------------------------------------
#define NQT_ (S_ / 64)   // 32 q-tiles per head
#define FSTR 72          // shorts per LDS row (144 B, 16B-multiple)
__global__ __launch_bounds__(256) void flash_attn_mfma_kernel(
    const unsigned short* __restrict__ qh, const unsigned short* __restrict__ khb,
    const unsigned short* __restrict__ vhb, unsigned short* __restrict__ aob)
{
    __shared__ __align__(16) short Qs[64][FSTR];
    __shared__ __align__(16) short Ks[64][FSTR];
    __shared__ __align__(16) short VsT[64][FSTR];  // [d][token]
    __shared__ __align__(16) short Ps[64][FSTR];
    int h = blockIdx.x >> 4;
    int p = blockIdx.x & 15;
    int tid = threadIdx.x;
    int wq = tid >> 6;              // wave id: q-rows [wq*16, wq*16+16)
    int lane = tid & 63;
    int ml = lane & 15, quad = lane >> 4;
    int srow = tid >> 2;            // staging row 0..63
    int sc = (tid & 3) * 16;        // staging chunk (16 shorts)
    const unsigned short* Qb = qh  + (size_t)h * S_ * HD_;
    const unsigned short* Kb = khb + (size_t)h * S_ * HD_;
    const unsigned short* Vb = vhb + (size_t)h * S_ * HD_;

    for (int half = 0; half < 2; half++) {
        int t = half ? (NQT_ - 1 - p) : p;
        int q0 = t * 64;

        // stage Q tile (written before loop-top barrier; prev-half reads done)
        {
            int4 v0 = *(const int4*)(Qb + (size_t)(q0 + srow) * HD_ + sc);
            int4 v1 = *(const int4*)(Qb + (size_t)(q0 + srow) * HD_ + sc + 8);
            *(int4*)(&Qs[srow][sc]) = v0;
            *(int4*)(&Qs[srow][sc + 8]) = v1;
        }

        float m[4], l[4];
        f32x4 o[4];
#pragma unroll
        for (int r = 0; r < 4; r++) { m[r] = -INFINITY; l[r] = 0.f; }
#pragma unroll
        for (int nb = 0; nb < 4; nb++) o[nb] = (f32x4){0.f, 0.f, 0.f, 0.f};

        for (int kt = 0; kt <= t; kt++) {
            int k0 = kt * 64;
            __syncthreads();   // prev PV reads of Ks/VsT/Ps done; Qs staged
            {
                int4 k0v = *(const int4*)(Kb + (size_t)(k0 + srow) * HD_ + sc);
                int4 k1v = *(const int4*)(Kb + (size_t)(k0 + srow) * HD_ + sc + 8);
                *(int4*)(&Ks[srow][sc]) = k0v;
                *(int4*)(&Ks[srow][sc + 8]) = k1v;
                union { int4 v[2]; short s[16]; } vv;
                vv.v[0] = *(const int4*)(Vb + (size_t)(k0 + srow) * HD_ + sc);
                vv.v[1] = *(const int4*)(Vb + (size_t)(k0 + srow) * HD_ + sc + 8);
#pragma unroll
                for (int jj = 0; jj < 16; jj++)
                    VsT[sc + jj][srow] = vv.s[jj];
            }
            __syncthreads();

            // ---- S = Q K^T ----
            f32x4 s[4];
#pragma unroll
            for (int nb = 0; nb < 4; nb++) s[nb] = (f32x4){0.f, 0.f, 0.f, 0.f};
            s16x8 aq0 = *(const s16x8*)(&Qs[wq * 16 + ml][quad * 8]);
            s16x8 aq1 = *(const s16x8*)(&Qs[wq * 16 + ml][32 + quad * 8]);
#pragma unroll
            for (int nb = 0; nb < 4; nb++) {
                s16x8 b0 = *(const s16x8*)(&Ks[nb * 16 + ml][quad * 8]);
                s16x8 b1 = *(const s16x8*)(&Ks[nb * 16 + ml][32 + quad * 8]);
                s[nb] = __builtin_amdgcn_mfma_f32_16x16x32_bf16(aq0, b0, s[nb], 0, 0, 0);
                s[nb] = __builtin_amdgcn_mfma_f32_16x16x32_bf16(aq1, b1, s[nb], 0, 0, 0);
            }

            // ---- online softmax (C layout: row=quad*4+r, col=nb*16+ml) ----
            float sv[4][4];
#pragma unroll
            for (int nb = 0; nb < 4; nb++)
#pragma unroll
                for (int r = 0; r < 4; r++) {
                    float v = s[nb][r];
                    if (kt == t && (nb * 16 + ml) > (wq * 16 + quad * 4 + r))
                        v = -1e30f;
                    sv[nb][r] = v;
                }
#pragma unroll
            for (int r = 0; r < 4; r++) {
                float rm = fmaxf(fmaxf(sv[0][r], sv[1][r]),
                                 fmaxf(sv[2][r], sv[3][r]));
#pragma unroll
                for (int off = 1; off < 16; off <<= 1)
                    rm = fmaxf(rm, __shfl_xor(rm, off));
                float mn = fmaxf(m[r], rm);
                float corr = __expf(m[r] - mn);
                m[r] = mn;
                float rs = 0.f;
#pragma unroll
                for (int nb = 0; nb < 4; nb++) {
                    float pe = __expf(sv[nb][r] - mn);
                    sv[nb][r] = pe;
                    rs += pe;
                }
#pragma unroll
                for (int off = 1; off < 16; off <<= 1)
                    rs += __shfl_xor(rs, off);
                l[r] = l[r] * corr + rs;
#pragma unroll
                for (int nb = 0; nb < 4; nb++) o[nb][r] *= corr;
            }

            // ---- P -> LDS (bf16, A-layout source for PV) ----
#pragma unroll
            for (int nb = 0; nb < 4; nb++)
#pragma unroll
                for (int r = 0; r < 4; r++)
                    Ps[wq * 16 + quad * 4 + r][nb * 16 + ml] =
                        (short)f2bf(sv[nb][r]);
            __syncthreads();

            // ---- O += P V ----
            s16x8 ap0 = *(const s16x8*)(&Ps[wq * 16 + ml][quad * 8]);
            s16x8 ap1 = *(const s16x8*)(&Ps[wq * 16 + ml][32 + quad * 8]);
#pragma unroll
            for (int nb = 0; nb < 4; nb++) {
                s16x8 b0 = *(const s16x8*)(&VsT[nb * 16 + ml][quad * 8]);
                s16x8 b1 = *(const s16x8*)(&VsT[nb * 16 + ml][32 + quad * 8]);
                o[nb] = __builtin_amdgcn_mfma_f32_16x16x32_bf16(ap0, b0, o[nb], 0, 0, 0);
                o[nb] = __builtin_amdgcn_mfma_f32_16x16x32_bf16(ap1, b1, o[nb], 0, 0, 0);
            }
        }

        // ---- epilogue: normalize, bf16, store to (T, D) ----
#pragma unroll
        for (int r = 0; r < 4; r++) {
            float inv = 1.0f / l[r];
            int row = q0 + wq * 16 + quad * 4 + r;
#pragma unroll
            for (int nb = 0; nb < 4; nb++)
                aob[(size_t)row * D_ + h * HD_ + nb * 16 + ml] =
                    f2bf(o[nb][r] * inv);
        }
    }
}

// ---------------------------------------------------------------------------
// expert scores + combine weights. One block per (chunk c, expert slot e).
// ---------------------------------------------------------------------------
__global__ __launch_bounds__(256) void expert_score_kernel(
    const float* __restrict__ xf, const float* __restrict__ keys,
    const float* __restrict__ scores,
    const float* __restrict__ head_probs,
    const float* __restrict__ score_probs,
    const int* __restrict__ indices, float* __restrict__ wbuf)
{
    __shared__ float Ks[KH_][D_];
    __shared__ float Xs[NT_][33];
    __shared__ float Ds[NT_][9];
    __shared__ float sp0[H_], sp1[H_], hp[H_];
    int blk = blockIdx.x;
    int c = blk / ET_, e = blk % ET_;
    int tid = threadIdx.x;
    int idx = indices[c * ET_ + e];
    int r = e / DE_;
    for (int i = tid; i < KH_ * D_; i += 256) {
        int kh = i >> 10, d = i & 1023;
        Ks[kh][d] = keys[((size_t)kh * D_ + d) * E_ + idx];
    }
    if (tid < H_) {
        int h = tid;
        sp0[h] = score_probs[((size_t)(0 * RE_ + r) * E_ + idx) * H_ + h];
        sp1[h] = score_probs[((size_t)(1 * RE_ + r) * E_ + idx) * H_ + h];
        hp[h]  = head_probs[((size_t)r * E_ + idx) * H_ + h];
    }
    float acc[4] = {0.f, 0.f, 0.f, 0.f};
    int tl = tid & 127;
    int g = tid >> 7;
    for (int d0 = 0; d0 < D_; d0 += 32) {
        __syncthreads();
        for (int i = tid; i < NT_ * 32; i += 256) {
            int t = i >> 5, d = i & 31;
            Xs[t][d] = xf[((size_t)(c * NT_ + t)) * D_ + d0 + d];
        }
        __syncthreads();
        for (int d = 0; d < 32; d++) {
            float aval = Xs[tl][d];
#pragma unroll
            for (int j = 0; j < 4; j++)
                acc[j] += aval * Ks[g * 4 + j][d0 + d];
        }
    }
    __syncthreads();
#pragma unroll
    for (int j = 0; j < 4; j++) Ds[tl][g * 4 + j] = acc[j];
    __syncthreads();
    if (tid < NT_) {
        int t = c * NT_ + tid;
        float wsum = 0.f;
#pragma unroll
        for (int h = 0; h < H_; h++) {
            float mval = Ds[tid][h >> 1];
            float sc = scores[((size_t)t * ET_ + e) * H_ + h];
            float z = sp0[h] * mval + sp1[h] * sc;
            float cmb = 1.0f / (1.0f + __expf(-z));
            wsum += cmb * hp[h];
        }
        wbuf[t * ET_ + e] = wsum;
    }
}

// ---------------------------------------------------------------------------
// MoE with rank-1 experts. One block per token.
// ---------------------------------------------------------------------------
__global__ __launch_bounds__(256) void moe_kernel(
    const float* __restrict__ xf, const float* __restrict__ xfi,
    const int* __restrict__ indices, const float* __restrict__ wbuf,
    const float* __restrict__ experts, float* __restrict__ out)
{
    int t = blockIdx.x, tid = threadIdx.x;
    int c = t / NT_;
    __shared__ int sidx[ET_];
    __shared__ float sw[ET_];
    __shared__ float r0[4], r1[4];
    if (tid < ET_) {
        sidx[tid] = indices[c * ET_ + tid];
        sw[tid] = wbuf[t * ET_ + tid];
    }
    float4 xv = ((const float4*)(xf + (size_t)t * D_))[tid];
    float acc[4] = {0.f, 0.f, 0.f, 0.f};
    __syncthreads();
    for (int e = 0; e < ET_; e++) {
        int idx = sidx[e];
        size_t base = (size_t)idx * D_;
        float4 w0 = *(const float4*)(experts + base + tid * 4);
        float4 w1 = *(const float4*)(experts + (size_t)E_ * D_ + base + tid * 4);
        float p0 = xv.x * w0.x + xv.y * w0.y + xv.z * w0.z + xv.w * w0.w;
        float p1 = xv.x * w1.x + xv.y * w1.y + xv.z * w1.z + xv.w * w1.w;
#pragma unroll
        for (int off = 32; off > 0; off >>= 1) {
            p0 += __shfl_xor(p0, off);
            p1 += __shfl_xor(p1, off);
        }
        if ((tid & 63) == 0) { r0[tid >> 6] = p0; r1[tid >> 6] = p1; }
        __syncthreads();
        float h0 = r0[0] + r0[1] + r0[2] + r0[3];
        float h1 = r1[0] + r1[1] + r1[2] + r1[3];
        __syncthreads();
        float act = h0 / (1.0f + __expf(-h0)) * h1 * sw[e];
        float4 w2 = *(const float4*)(experts + (size_t)2 * E_ * D_ + base + tid * 4);
        acc[0] += act * w2.x;
        acc[1] += act * w2.y;
        acc[2] += act * w2.z;
        acc[3] += act * w2.w;
    }
    size_t o = (size_t)t * D_ + tid * 4;
    float4 rv = *(const float4*)(xfi + o);
    float4 ov;
    ov.x = acc[0] + rv.x;
    ov.y = acc[1] + rv.y;
    ov.z = acc[2] + rv.z;
    ov.w = acc[3] + rv.w;
    *(float4*)(out + o) = ov;
}

// ---------------------------------------------------------------------------
extern "C" void kernel_launch(void* const* d_in, const int* in_sizes, int n_in,
                              void* d_out, int out_size, void* d_ws, size_t ws_size,
                              hipStream_t stream)
{
    (void)in_sizes; (void)n_in; (void)out_size; (void)ws_size;
    const float* x_input     = (const float*)d_in[0];
    const int*   indices     = (const int*)d_in[1];
    const float* scores      = (const float*)d_in[2];
    const float* attn_w      = (const float*)d_in[3];
    const float* attn_out_w  = (const float*)d_in[4];
    const float* attn_norm_w = (const float*)d_in[5];
    const float* ffn_norm_w  = (const float*)d_in[6];
    const float* ffn_experts = (const float*)d_in[7];
    const float* keys        = (const float*)d_in[8];
    const float* head_probs  = (const float*)d_in[9];
    const float* score_probs = (const float*)d_in[10];
    float* out = (float*)d_out;

    float* ws = (float*)d_ws;
    const size_t MF = 1024 * 1024;
    // Region map (floats), peak 12M floats = 48 MB:
    // A [0,6M): qkv (gemm1 out); after qkv_prep reused as:
    //    aob [0,1M) bf16 | xfi [1M,3M) | xf [3M,5M) | wbuf [5M,..) | woutT [5.5M,6M) bf16
    // B [6M,8M): xnb bf16 (steps 1-3) -> qh bf16 (step 4+)
    // C [8M,10M): wqkvT bf16 (steps 2-3) -> khb bf16 (step 4+)
    // D [10M,12M): vhb bf16
    float* qkv            = ws;
    unsigned short* aob   = (unsigned short*)ws;
    float* xfi            = ws + 1 * MF;
    float* xf             = ws + 3 * MF;
    float* wbuf           = ws + 5 * MF;
    unsigned short* woutT = (unsigned short*)(ws + 5 * MF + 512 * 1024);
    unsigned short* xnb   = (unsigned short*)(ws + 6 * MF);
    unsigned short* qh    = (unsigned short*)(ws + 6 * MF);
    unsigned short* wqkvT = (unsigned short*)(ws + 8 * MF);
    unsigned short* khb   = (unsigned short*)(ws + 8 * MF);
    unsigned short* vhb   = (unsigned short*)(ws + 10 * MF);

    // 1) rmsnorm -> bf16 A
    rmsnorm_bf16_kernel<<<T_, 256, 0, stream>>>(x_input, attn_norm_w, xnb);

    // 2) attn_w (1024 x 3072) -> wqkvT [3072][1024] bf16
    {
        dim3 g(3 * D_ / 32, D_ / 32);
        convt_kernel<<<g, 256, 0, stream>>>(attn_w, wqkvT, D_, 3 * D_);
    }

    // 3) qkv = xnb @ attn_w   (MFMA)
    {
        dim3 g(3 * D_ / 128, T_ / 128);
        mfma_gemm_kernel<0><<<g, 256, 0, stream>>>(xnb, wqkvT, nullptr, qkv,
                                                   T_, 3 * D_, D_);
    }

    // 4) split + l2norm + rope -> bf16 q/k/v
    qkv_prep_kernel<<<T_ * NH_, 64, 0, stream>>>(qkv, qh, khb, vhb);

    // 5) MFMA flash attention -> aob bf16
    flash_attn_mfma_kernel<<<NH_ * 16, 256, 0, stream>>>(qh, khb, vhb, aob);

    // 6) attn_out_w (1024 x 1024) -> woutT [1024][1024] bf16
    {
        dim3 g(D_ / 32, D_ / 32);
        convt_kernel<<<g, 256, 0, stream>>>(attn_out_w, woutT, D_, D_);
    }

    // 7) xfi = aob @ attn_out_w + x_input   (MFMA + residual)
    {
        dim3 g(D_ / 128, T_ / 128);
        mfma_gemm_kernel<1><<<g, 256, 0, stream>>>(aob, woutT, x_input, xfi,
                                                   T_, D_, D_);
    }

    // 8) rmsnorm fp32
    rmsnorm_kernel<<<T_, 256, 0, stream>>>(xfi, ffn_norm_w, xf);

    // 9) expert scores -> combine weights
    expert_score_kernel<<<BC_ * ET_, 256, 0, stream>>>(
        xf, keys, scores, head_probs, score_probs, indices, wbuf);

    // 10) MoE + final residual
    moe_kernel<<<T_, 256, 0, stream>>>(xf, xfi, indices, wbuf, ffn_experts, out);
}